// Round 11
// baseline (103.790 us; speedup 1.0000x reference)
//
#include <hip/hip_runtime.h>
#include <math.h>

constexpr int S_ = 4096;
constexpr int B_ = 64;
constexpr int H_ = 256;
constexpr int NB_ = 1024;          // kB blocks, 4 s-rows each
constexpr float SHIFT = 60.0f;     // fixed softmax shift: exp(sc-SHIFT), exact ratios

// ws float layout:
// 0     : dW    [B][H]    = 16384
// 16384 : pc    [B]       = 64
// 16448 : swin  [B][8]    = 512     (raw in-window scores, slot = s & 7)
// 16960 : lpart [B][NB_]  = 65536   (per-block sums of exp(sc-SHIFT))

// kA: 64 blocks x 1024 threads: dW[b][:] = d_b @ W_a; pc[b] via W_p path.
// THIS ROUND: launched 5x as an attribution probe (idempotent).
__global__ __launch_bounds__(1024) void kA_prep(const float* __restrict__ d,
                                                const float* __restrict__ W_a,
                                                const float* __restrict__ W_p,
                                                const float* __restrict__ v_p,
                                                float* __restrict__ dW,
                                                float* __restrict__ pc) {
  const int b = blockIdx.x;
  const int t = threadIdx.x;
  const int h = t & 255;
  const int kc = t >> 8;                  // 4-way k split
  const float* db = d + b * H_;
  float aa = 0.f, ap = 0.f;
#pragma unroll 8
  for (int k = kc * 64; k < kc * 64 + 64; ++k) {
    float dv = db[k];
    aa = fmaf(dv, W_a[k * H_ + h], aa);
    ap = fmaf(dv, W_p[k * H_ + h], ap);
  }
  __shared__ float redA[1024];
  __shared__ float redB[1024];
  redA[t] = aa;
  redB[t] = ap;
  __syncthreads();
  if (t < 256) {
    float dwa = redA[t] + redA[t + 256] + redA[t + 512] + redA[t + 768];
    float dwp = redB[t] + redB[t + 256] + redB[t + 512] + redB[t + 768];
    dW[b * H_ + t] = dwa;
    redA[t] = tanhf(dwp) * v_p[t];
  }
  __syncthreads();
  for (int st = 128; st > 0; st >>= 1) {
    if (t < st) redA[t] += redA[t + st];
    __syncthreads();
  }
  if (t == 0) pc[b] = (float)S_ / (1.f + expf(-redA[0]));
}

// kB: streaming dot-product core; tail emits exp-sum partials +
// in-window score stash + coalesced zero-fill of this tile's w_out slice.
__global__ __launch_bounds__(256) void kB_scores(const float* __restrict__ e,
                                                 const float* __restrict__ dW,
                                                 const float* __restrict__ pc,
                                                 float* __restrict__ lpart,
                                                 float* __restrict__ swin,
                                                 float* __restrict__ w_out) {
  int t = threadIdx.x;
  int wave = t >> 6;
  int lane = t & 63;
  int bl = lane >> 2;
  int sub = lane & 3;
  int b = wave * 16 + bl;
  int s0 = blockIdx.x * 4;

  const float4* dW4 = (const float4*)(dW + b * H_);
  float4 wreg[16];
#pragma unroll
  for (int j = 0; j < 16; ++j) wreg[j] = dW4[sub + 4 * j];

  __shared__ float tile[4][64];
#pragma unroll
  for (int r = 0; r < 4; ++r) {
    const float4* erow = (const float4*)(e + ((size_t)(s0 + r) * B_ + b) * H_);
    float acc = 0.f;
#pragma unroll
    for (int half = 0; half < 2; ++half) {
      float4 ev[8];
#pragma unroll
      for (int j = 0; j < 8; ++j) ev[j] = erow[sub + 4 * (half * 8 + j)];
#pragma unroll
      for (int j = 0; j < 8; ++j) {
        const float4 wv = wreg[half * 8 + j];
        acc = fmaf(ev[j].x, wv.x, fmaf(ev[j].y, wv.y,
              fmaf(ev[j].z, wv.z, fmaf(ev[j].w, wv.w, acc))));
      }
    }
    acc += __shfl_xor(acc, 1, 64);
    acc += __shfl_xor(acc, 2, 64);
    if (sub == 0) tile[r][b] = acc;
  }
  __syncthreads();
  if (t < 64) {
    const int bb = t;
    float lp = expf(tile[0][bb] - SHIFT) + expf(tile[1][bb] - SHIFT) +
               expf(tile[2][bb] - SHIFT) + expf(tile[3][bb] - SHIFT);
    lpart[bb * NB_ + blockIdx.x] = lp;
    const float pcb = pc[bb];
#pragma unroll
    for (int r = 0; r < 4; ++r) {
      int s = s0 + r;
      if (fabsf(pcb - (float)s) <= 2.f) swin[bb * 8 + (s & 7)] = tile[r][bb];
    }
  }
  // coalesced zero-fill of this tile's w_out slice (kD overwrites windows)
  {
    int r = t >> 6, bz = t & 63;
    w_out[(size_t)(s0 + r) * B_ + bz] = 0.f;
  }
}

// kD: one block per b. l = sum of partials (coalesced 4KB); window w values ->
// w_out; context gather; fused linear + ReLU.
__global__ __launch_bounds__(1024) void kD_out(const float* __restrict__ lpart,
                                               const float* __restrict__ swin,
                                               const float* __restrict__ pcv,
                                               const float* __restrict__ e,
                                               const float* __restrict__ d,
                                               const float* __restrict__ lin_w,
                                               const float* __restrict__ lin_b,
                                               float* __restrict__ out,
                                               float* __restrict__ w_out) {
  const int b = blockIdx.x;
  const int t = threadIdx.x;
  __shared__ float red[1024];
  red[t] = lpart[b * NB_ + t];
  __syncthreads();
  for (int st = 512; st > 0; st >>= 1) {
    if (t < st) red[t] += red[t + st];
    __syncthreads();
  }
  const float invL = 1.f / red[0];
  const float pcb = pcv[b];
  const int s0 = max(0, (int)ceilf(pcb - 2.f));
  const int s1 = min(S_ - 1, (int)floorf(pcb + 2.f));
  const int nw = s1 - s0 + 1;             // <= 5
  __shared__ float wsh[8];
  __shared__ float xbuf[512];
  if (t < nw) {
    const int s = s0 + t;
    const float diff = pcb - (float)s;
    const float w = expf(swin[b * 8 + (s & 7)] - SHIFT) * invL * expf(-0.5f * diff * diff);
    w_out[(size_t)s * B_ + b] = w;
    wsh[t] = w;
  }
  __syncthreads();
  if (t < 256) {
    float ctx = 0.f;
    for (int j = 0; j < nw; ++j)
      ctx = fmaf(wsh[j], e[((size_t)(s0 + j) * B_ + b) * H_ + t], ctx);
    xbuf[t] = ctx;
    xbuf[256 + t] = d[b * H_ + t];
  }
  __syncthreads();
  const int h = t >> 2, part = t & 3;
  const float4* lw = (const float4*)(lin_w + h * 2 * H_) + part * 32;
  const float4* xv = (const float4*)xbuf + part * 32;
  float acc = 0.f;
#pragma unroll 8
  for (int k = 0; k < 32; ++k) {
    float4 a4 = lw[k];
    float4 b4 = xv[k];
    acc += a4.x * b4.x + a4.y * b4.y + a4.z * b4.z + a4.w * b4.w;
  }
  red[t] = acc;
  __syncthreads();
  if (t < 256) {
    float r = red[4 * t] + red[4 * t + 1] + red[4 * t + 2] + red[4 * t + 3] + lin_b[t];
    out[b * H_ + t] = fmaxf(r, 0.f);
  }
}

extern "C" void kernel_launch(void* const* d_in, const int* in_sizes, int n_in,
                              void* d_out, int out_size, void* d_ws, size_t ws_size,
                              hipStream_t stream) {
  const float* e     = (const float*)d_in[0];
  const float* dd    = (const float*)d_in[1];
  const float* W_a   = (const float*)d_in[2];
  const float* W_p   = (const float*)d_in[3];
  const float* v_p   = (const float*)d_in[4];
  const float* lin_w = (const float*)d_in[5];
  const float* lin_b = (const float*)d_in[6];

  float* out   = (float*)d_out;        // [1,B,H] = 16384 floats
  float* w_out = out + B_ * H_;        // [S,B]   = 262144 floats

  float* ws    = (float*)d_ws;
  float* dW    = ws;
  float* pc    = ws + 16384;
  float* swin  = ws + 16448;
  float* lpart = ws + 16960;

  // ATTRIBUTION PROBE: kA launched 5x (idempotent).
  // dur - 71.2 = 4 * (t_kA + gap); kA physics-bounded at 2-3 us -> pins gap.
  kA_prep<<<B_, 1024, 0, stream>>>(dd, W_a, W_p, v_p, dW, pc);
  kA_prep<<<B_, 1024, 0, stream>>>(dd, W_a, W_p, v_p, dW, pc);
  kA_prep<<<B_, 1024, 0, stream>>>(dd, W_a, W_p, v_p, dW, pc);
  kA_prep<<<B_, 1024, 0, stream>>>(dd, W_a, W_p, v_p, dW, pc);
  kA_prep<<<B_, 1024, 0, stream>>>(dd, W_a, W_p, v_p, dW, pc);
  kB_scores<<<NB_, 256, 0, stream>>>(e, dW, pc, lpart, swin, w_out);
  kD_out<<<B_, 1024, 0, stream>>>(lpart, swin, pc, e, dd, lin_w, lin_b, out, w_out);
}

// Round 12
// 87.472 us; speedup vs baseline: 1.1866x; 1.1866x over previous
//
#include <hip/hip_runtime.h>
#include <math.h>

constexpr int S_ = 4096;
constexpr int B_ = 64;
constexpr int H_ = 256;
constexpr int NB_ = 1024;          // kB blocks, 4 s-rows each
constexpr float SHIFT = 60.0f;     // fixed softmax shift: exp(sc-SHIFT), exact ratios

// ws float layout:
// 0     : dW    [B][H] = 16384
// 16384 : pc    [B]    = 64
// 16448 : Lacc  [B][16] = 1024   (f32 atomic accumulators, one cacheline per b; memset 0)
// 17472 : counter (uint, padded to 64 floats; memset 0)
// 17536 : swinG [B][8] = 512     (raw in-window scores via atomicExch, slot = s & 7)

// kA: 64 blocks x 1024 threads: dW[b][:] = d_b @ W_a; pc[b] via W_p path;
// also zero-fills w_out (16KB/block) so kB needs no zero pass and kD no memset.
__global__ __launch_bounds__(1024) void kA_prep(const float* __restrict__ d,
                                                const float* __restrict__ W_a,
                                                const float* __restrict__ W_p,
                                                const float* __restrict__ v_p,
                                                float* __restrict__ dW,
                                                float* __restrict__ pc,
                                                float* __restrict__ w_out) {
  const int b = blockIdx.x;
  const int t = threadIdx.x;
  const int h = t & 255;
  const int kc = t >> 8;                  // 4-way k split
  const float* db = d + b * H_;
  float aa = 0.f, ap = 0.f;
#pragma unroll 8
  for (int k = kc * 64; k < kc * 64 + 64; ++k) {
    float dv = db[k];
    aa = fmaf(dv, W_a[k * H_ + h], aa);
    ap = fmaf(dv, W_p[k * H_ + h], ap);
  }
  // zero-fill this block's 16KB slice of w_out (coalesced float4)
  {
    float4 z = make_float4(0.f, 0.f, 0.f, 0.f);
    ((float4*)w_out)[blockIdx.x * 1024 + t] = z;
  }
  __shared__ float redA[1024];
  __shared__ float redB[1024];
  redA[t] = aa;
  redB[t] = ap;
  __syncthreads();
  if (t < 256) {
    float dwa = redA[t] + redA[t + 256] + redA[t + 512] + redA[t + 768];
    float dwp = redB[t] + redB[t + 256] + redB[t + 512] + redB[t + 768];
    dW[b * H_ + t] = dwa;
    redA[t] = tanhf(dwp) * v_p[t];
  }
  __syncthreads();
  for (int st = 128; st > 0; st >>= 1) {
    if (t < st) redA[t] += redA[t + st];
    __syncthreads();
  }
  if (t == 0) pc[b] = (float)S_ / (1.f + expf(-redA[0]));
}

// kB_fused: streaming scores (proven core) + atomic L accumulation + window
// score stash; last-64-arriving blocks each finalize one b (w_out window,
// context, fused linear+ReLU). NO fences anywhere:
//   - cross-block data flows only through device atomics (coherent point);
//   - __syncthreads drains each thread's vmcnt before t0 bumps the counter;
//   - finisher spins on a RELAXED agent atomic load (no cache-inval thrash).
__global__ __launch_bounds__(256) void kB_fused(const float* __restrict__ e,
                                                const float* __restrict__ dW,
                                                const float* __restrict__ pc,
                                                const float* __restrict__ d,
                                                const float* __restrict__ lin_w,
                                                const float* __restrict__ lin_b,
                                                float* __restrict__ Lacc,
                                                float* __restrict__ swinG,
                                                unsigned int* __restrict__ counter,
                                                float* __restrict__ out,
                                                float* __restrict__ w_out) {
  const int t = threadIdx.x;
  const int blk = blockIdx.x;
  __shared__ float tile[4][64];
  __shared__ unsigned int ordS;

  {  // ---- main phase: 4 s-rows x 64 b dot products (R10 core) ----
    const int wave = t >> 6, lane = t & 63;
    const int bl = lane >> 2, sub = lane & 3;
    const int b = wave * 16 + bl;
    const int s0 = blk * 4;
    const float4* dW4 = (const float4*)(dW + b * H_);
    float4 wreg[16];
#pragma unroll
    for (int j = 0; j < 16; ++j) wreg[j] = dW4[sub + 4 * j];
#pragma unroll
    for (int r = 0; r < 4; ++r) {
      const float4* erow = (const float4*)(e + ((size_t)(s0 + r) * B_ + b) * H_);
      float acc = 0.f;
#pragma unroll
      for (int half = 0; half < 2; ++half) {
        float4 ev[8];
#pragma unroll
        for (int j = 0; j < 8; ++j) ev[j] = erow[sub + 4 * (half * 8 + j)];
#pragma unroll
        for (int j = 0; j < 8; ++j) {
          const float4 wv = wreg[half * 8 + j];
          acc = fmaf(ev[j].x, wv.x, fmaf(ev[j].y, wv.y,
                fmaf(ev[j].z, wv.z, fmaf(ev[j].w, wv.w, acc))));
        }
      }
      acc += __shfl_xor(acc, 1, 64);
      acc += __shfl_xor(acc, 2, 64);
      if (sub == 0) tile[r][b] = acc;
    }
  }
  __syncthreads();
  if (t < 64) {
    const int bb = t;
    const int s0 = blk * 4;
    float lp = expf(tile[0][bb] - SHIFT) + expf(tile[1][bb] - SHIFT) +
               expf(tile[2][bb] - SHIFT) + expf(tile[3][bb] - SHIFT);
    atomicAdd(&Lacc[bb * 16], lp);                 // 64 distinct cachelines
    const float pcb = pc[bb];
#pragma unroll
    for (int r = 0; r < 4; ++r) {
      int s = s0 + r;
      if (fabsf(pcb - (float)s) <= 2.f)
        atomicExch(&swinG[bb * 8 + (s & 7)], tile[r][bb]);
    }
  }
  __syncthreads();   // drains vmcnt per thread -> all atomics at coherent point
  if (t == 0) ordS = atomicAdd(counter, 1u);
  __syncthreads();
  const unsigned int ord = ordS;
  if (ord < (unsigned)(NB_ - B_)) return;          // not a finisher
  const int bf = (int)(ord - (NB_ - B_));

  if (t == 0) {
    while (__hip_atomic_load(counter, __ATOMIC_RELAXED, __HIP_MEMORY_SCOPE_AGENT)
           < (unsigned)NB_)
      __builtin_amdgcn_s_sleep(2);
  }
  __syncthreads();

  // ---- finisher for b = bf ----
  const float pcb = pc[bf];
  const float L = __hip_atomic_load(&Lacc[bf * 16], __ATOMIC_RELAXED,
                                    __HIP_MEMORY_SCOPE_AGENT);
  const float invL = 1.f / L;
  const int s0 = max(0, (int)ceilf(pcb - 2.f));
  const int s1 = min(S_ - 1, (int)floorf(pcb + 2.f));
  const int nw = s1 - s0 + 1;                      // <= 5
  __shared__ float wsh[8];
  __shared__ float xbuf[512];
  if (t < nw) {
    const int s = s0 + t;
    const float diff = pcb - (float)s;
    const float sw = __hip_atomic_load(&swinG[bf * 8 + (s & 7)], __ATOMIC_RELAXED,
                                       __HIP_MEMORY_SCOPE_AGENT);
    const float w = expf(sw - SHIFT) * invL * expf(-0.5f * diff * diff);
    w_out[(size_t)s * B_ + bf] = w;
    wsh[t] = w;
  }
  __syncthreads();
  {  // context gather, t = h
    float ctx = 0.f;
    for (int j = 0; j < nw; ++j)
      ctx = fmaf(wsh[j], e[((size_t)(s0 + j) * B_ + bf) * H_ + t], ctx);
    xbuf[t] = ctx;
    xbuf[256 + t] = d[bf * H_ + t];
  }
  __syncthreads();
  {  // fused linear + ReLU, t = output h
    float acc = lin_b[t];
    const float4* lw = (const float4*)(lin_w + t * 2 * H_);
    const float4* xv = (const float4*)xbuf;
#pragma unroll 8
    for (int k = 0; k < 128; ++k) {
      float4 a4 = lw[k];
      float4 b4 = xv[k];
      acc += a4.x * b4.x + a4.y * b4.y + a4.z * b4.z + a4.w * b4.w;
    }
    out[bf * H_ + t] = fmaxf(acc, 0.f);
  }
}

extern "C" void kernel_launch(void* const* d_in, const int* in_sizes, int n_in,
                              void* d_out, int out_size, void* d_ws, size_t ws_size,
                              hipStream_t stream) {
  const float* e     = (const float*)d_in[0];
  const float* dd    = (const float*)d_in[1];
  const float* W_a   = (const float*)d_in[2];
  const float* W_p   = (const float*)d_in[3];
  const float* v_p   = (const float*)d_in[4];
  const float* lin_w = (const float*)d_in[5];
  const float* lin_b = (const float*)d_in[6];

  float* out   = (float*)d_out;        // [1,B,H] = 16384 floats
  float* w_out = out + B_ * H_;        // [S,B]   = 262144 floats

  float* ws    = (float*)d_ws;
  float* dW    = ws;
  float* pc    = ws + 16384;
  float* Lacc  = ws + 16448;
  unsigned int* counter = (unsigned int*)(ws + 17472);
  float* swinG = ws + 17536;

  // zero Lacc + counter (one contiguous region)
  hipMemsetAsync(ws + 16448, 0, (17536 - 16448) * sizeof(float), stream);
  kA_prep<<<B_, 1024, 0, stream>>>(dd, W_a, W_p, v_p, dW, pc, w_out);
  kB_fused<<<NB_, 256, 0, stream>>>(e, dW, pc, dd, lin_w, lin_b,
                                    Lacc, swinG, counter, out, w_out);
}

// Round 13
// 69.779 us; speedup vs baseline: 1.4874x; 1.2535x over previous
//
#include <hip/hip_runtime.h>
#include <math.h>

constexpr int S_ = 4096;
constexpr int B_ = 64;
constexpr int H_ = 256;
constexpr int NCH = 16;            // s-chunks per b
constexpr int ROWS = S_ / NCH;     // 256 rows per block
constexpr float SHIFT = 60.0f;     // fixed softmax shift (exact ratios; |sc| ~ N(0,16))

// ws float layout:
// 0     : dW    [B][H]   = 16384  (written by chunk-0 block of each b)
// 16384 : lpart [B][NCH] = 1024

// kMain: 1024 blocks = (chunk c = bid>>6, b = bid&63), 256 threads.
// Phase 0: compute dW[b] in-block (wave w: k in [64w,64w+64), lane: h-quad).
// Phase 1: stream this chunk's 256 e-rows with the PROVEN access pattern
//          (16 rows x 64B per instr, 2-shfl quad reduce), accumulate
//          sum(exp(sc-SHIFT)) -> lpart[b][c]. Plus flat w_out zero-fill.
__global__ __launch_bounds__(256) void kMain(const float* __restrict__ e,
                                             const float* __restrict__ d,
                                             const float* __restrict__ W_a,
                                             float* __restrict__ dW,
                                             float* __restrict__ lpart,
                                             float* __restrict__ w_out) {
  const int bid = blockIdx.x;
  const int b = bid & 63;
  const int c = bid >> 6;
  const int t = threadIdx.x;
  const int w = t >> 6;
  const int lane = t & 63;

  __shared__ float4 part[4][64];
  __shared__ float4 dw4[64];
  __shared__ float lred[64];

  // ---- phase 0: dW[b] = d_b @ W_a ----
  {
    const float* db = d + b * H_;
    const float4* Wa4 = (const float4*)W_a;
    float4 acc = make_float4(0.f, 0.f, 0.f, 0.f);
#pragma unroll 8
    for (int i = 0; i < 64; ++i) {
      const int k = w * 64 + i;
      const float dv = db[k];                 // wave-uniform -> scalar load
      const float4 wa = Wa4[k * 64 + lane];   // 1KB coalesced per instr
      acc.x = fmaf(dv, wa.x, acc.x);
      acc.y = fmaf(dv, wa.y, acc.y);
      acc.z = fmaf(dv, wa.z, acc.z);
      acc.w = fmaf(dv, wa.w, acc.w);
    }
    part[w][lane] = acc;
    __syncthreads();
    if (t < 64) {
      float4 a0 = part[0][t], a1 = part[1][t], a2 = part[2][t], a3 = part[3][t];
      float4 r = make_float4(a0.x + a1.x + a2.x + a3.x,
                             a0.y + a1.y + a2.y + a3.y,
                             a0.z + a1.z + a2.z + a3.z,
                             a0.w + a1.w + a2.w + a3.w);
      dw4[t] = r;
      if (c == 0) ((float4*)(dW + b * H_))[t] = r;   // stash for kD
    }
    __syncthreads();
  }

  // ---- phase 1: stream 256 rows of e for this (b, chunk) ----
  const int rr = lane >> 2;
  const int sub = lane & 3;
  float4 wreg[16];
#pragma unroll
  for (int j = 0; j < 16; ++j) wreg[j] = dw4[sub + 4 * j];   // LDS broadcast

  float lsum = 0.f;
#pragma unroll 1
  for (int p = 0; p < 4; ++p) {
    const int s = c * ROWS + p * 64 + w * 16 + rr;
    const float4* erow = (const float4*)(e + ((size_t)s * B_ + b) * H_);
    float acc = 0.f;
#pragma unroll
    for (int half = 0; half < 2; ++half) {
      float4 ev[8];
#pragma unroll
      for (int j = 0; j < 8; ++j) ev[j] = erow[sub + 4 * (half * 8 + j)];
#pragma unroll
      for (int j = 0; j < 8; ++j) {
        const float4 wv = wreg[half * 8 + j];
        acc = fmaf(ev[j].x, wv.x, fmaf(ev[j].y, wv.y,
              fmaf(ev[j].z, wv.z, fmaf(ev[j].w, wv.w, acc))));
      }
    }
    acc += __shfl_xor(acc, 1, 64);
    acc += __shfl_xor(acc, 2, 64);
    if (sub == 0) lsum += expf(acc - SHIFT);
  }
  if (sub == 0) lred[w * 16 + rr] = lsum;
  __syncthreads();
  if (t < 64) {
    float v = lred[t];
#pragma unroll
    for (int off = 32; off > 0; off >>= 1) v += __shfl_xor(v, off, 64);
    if (t == 0) lpart[b * NCH + c] = v;
  }
  // flat coalesced zero-fill of w_out (1024 blocks x 256 floats = full 1MB)
  w_out[bid * 256 + t] = 0.f;
}

// kD: 64 blocks x 1024 threads, one b each. Recomputes pc (W_p path),
// re-scores the <=5 window rows from e + dW, writes window w values,
// context gather, fused linear + ReLU.
__global__ __launch_bounds__(1024) void kD(const float* __restrict__ e,
                                           const float* __restrict__ d,
                                           const float* __restrict__ W_p,
                                           const float* __restrict__ v_p,
                                           const float* __restrict__ lin_w,
                                           const float* __restrict__ lin_b,
                                           const float* __restrict__ dW,
                                           const float* __restrict__ lpart,
                                           float* __restrict__ out,
                                           float* __restrict__ w_out) {
  const int b = blockIdx.x;
  const int t = threadIdx.x;
  __shared__ float red[1024];
  __shared__ float sstate[2];   // [0]=pc, [1]=invL
  __shared__ float scW[8];
  __shared__ float wsh[8];
  __shared__ float xbuf[512];

  // ---- pc[b] via W_p path (4-way k-split) + L from lpart ----
  {
    const int h = t & 255, kc = t >> 8;
    const float* db = d + b * H_;
    float ap = 0.f;
#pragma unroll 8
    for (int k = kc * 64; k < kc * 64 + 64; ++k)
      ap = fmaf(db[k], W_p[k * H_ + h], ap);
    red[t] = ap;
    __syncthreads();
    if (t < 256) {
      float sp = red[t] + red[t + 256] + red[t + 512] + red[t + 768];
      red[t] = tanhf(sp) * v_p[t];
    }
    __syncthreads();
    for (int st = 128; st > 0; st >>= 1) {
      if (t < st) red[t] += red[t + st];
      __syncthreads();
    }
    if (t == 0) {
      sstate[0] = (float)S_ / (1.f + expf(-red[0]));
      float L = 0.f;
#pragma unroll
      for (int j = 0; j < NCH; ++j) L += lpart[b * NCH + j];
      sstate[1] = 1.f / L;
    }
    __syncthreads();
  }
  const float pcb = sstate[0];
  const float invL = sstate[1];
  const int s0 = max(0, (int)ceilf(pcb - 2.f));
  const int s1 = min(S_ - 1, (int)floorf(pcb + 2.f));
  const int nw = s1 - s0 + 1;             // 2..5

  // ---- window scores: wave j dots row s0+j with dW[b] ----
  if (t < nw * 64) {
    const int j = t >> 6, lane = t & 63;
    const float4 ev = ((const float4*)(e + ((size_t)(s0 + j) * B_ + b) * H_))[lane];
    const float4 wv = ((const float4*)(dW + b * H_))[lane];
    float p = ev.x * wv.x + ev.y * wv.y + ev.z * wv.z + ev.w * wv.w;
#pragma unroll
    for (int off = 32; off > 0; off >>= 1) p += __shfl_xor(p, off, 64);
    if (lane == 0) scW[j] = p;
  }
  __syncthreads();
  if (t < nw) {
    const int s = s0 + t;
    const float diff = pcb - (float)s;
    const float wv = expf(scW[t] - SHIFT) * invL * expf(-0.5f * diff * diff);
    wsh[t] = wv;
    w_out[(size_t)s * B_ + b] = wv;
  }
  __syncthreads();
  if (t < 256) {
    float ctx = 0.f;
    for (int j = 0; j < nw; ++j)
      ctx = fmaf(wsh[j], e[((size_t)(s0 + j) * B_ + b) * H_ + t], ctx);
    xbuf[t] = ctx;
    xbuf[256 + t] = d[b * H_ + t];
  }
  __syncthreads();
  // ---- fused linear + ReLU (4-way split per output h) ----
  const int h = t >> 2, prt = t & 3;
  const float4* lw = (const float4*)(lin_w + h * 2 * H_) + prt * 32;
  const float4* xv = (const float4*)xbuf + prt * 32;
  float acc = 0.f;
#pragma unroll 8
  for (int k = 0; k < 32; ++k) {
    float4 a4 = lw[k], b4 = xv[k];
    acc += a4.x * b4.x + a4.y * b4.y + a4.z * b4.z + a4.w * b4.w;
  }
  red[t] = acc;
  __syncthreads();
  if (t < 256) {
    float r = red[4 * t] + red[4 * t + 1] + red[4 * t + 2] + red[4 * t + 3] + lin_b[t];
    out[b * H_ + t] = fmaxf(r, 0.f);
  }
}

extern "C" void kernel_launch(void* const* d_in, const int* in_sizes, int n_in,
                              void* d_out, int out_size, void* d_ws, size_t ws_size,
                              hipStream_t stream) {
  const float* e     = (const float*)d_in[0];
  const float* dd    = (const float*)d_in[1];
  const float* W_a   = (const float*)d_in[2];
  const float* W_p   = (const float*)d_in[3];
  const float* v_p   = (const float*)d_in[4];
  const float* lin_w = (const float*)d_in[5];
  const float* lin_b = (const float*)d_in[6];

  float* out   = (float*)d_out;        // [1,B,H] = 16384 floats
  float* w_out = out + B_ * H_;        // [S,B]   = 262144 floats

  float* ws    = (float*)d_ws;
  float* dW    = ws;
  float* lpart = ws + 16384;

  kMain<<<B_ * NCH, 256, 0, stream>>>(e, dd, W_a, dW, lpart, w_out);
  kD<<<B_, 1024, 0, stream>>>(e, dd, W_p, v_p, lin_w, lin_b, dW, lpart, out, w_out);
}